// Round 2
// baseline (223.049 us; speedup 1.0000x reference)
//
#include <hip/hip_runtime.h>
#include <hip/hip_bf16.h>
#include <math.h>

typedef __attribute__((ext_vector_type(4))) float f32x4;
typedef __bf16 bf16x8 __attribute__((ext_vector_type(8)));
typedef unsigned short u16;
typedef void __attribute__((address_space(1))) * as1p;
typedef void __attribute__((address_space(3))) * as3p;

#define BAR() __builtin_amdgcn_s_barrier()
#define LGKM0() asm volatile("s_waitcnt lgkmcnt(0)" ::: "memory")
#define VMW4() asm volatile("s_waitcnt vmcnt(4)" ::: "memory")
#define VMW0() asm volatile("s_waitcnt vmcnt(0)" ::: "memory")

__device__ __forceinline__ unsigned short f2bf(float f) {
    union { float f; unsigned int u; } v; v.f = f;
    unsigned int u = v.u;
    u += 0x7fffu + ((u >> 16) & 1u);   // RNE
    return (unsigned short)(u >> 16);
}

// ---------- prepass: fp32 -> bf16 for X, h_prev ----------
__global__ void cvt_xh(const float* __restrict__ x, const float* __restrict__ h,
                       u16* __restrict__ xb, u16* __restrict__ hb, int n4) {
    int i = blockIdx.x * blockDim.x + threadIdx.x;
    int stride = gridDim.x * blockDim.x;
    const float4* x4 = (const float4*)x;
    const float4* h4 = (const float4*)h;
    ushort4* xb4 = (ushort4*)xb;
    ushort4* hb4 = (ushort4*)hb;
    for (; i < n4; i += stride) {
        float4 v = x4[i];
        xb4[i] = make_ushort4(f2bf(v.x), f2bf(v.y), f2bf(v.z), f2bf(v.w));
        float4 w = h4[i];
        hb4[i] = make_ushort4(f2bf(w.x), f2bf(w.y), f2bf(w.z), f2bf(w.w));
    }
}

// ---------- prepass: transpose+convert weight fp32 [1024][512] -> bf16 [512][1024] ----------
__global__ void tr_cvt(const float* __restrict__ src, u16* __restrict__ dst) {
    __shared__ float t[32][33];
    int n0 = blockIdx.x * 32;
    int k0 = blockIdx.y * 32;
    int tx = threadIdx.x, ty = threadIdx.y;
#pragma unroll
    for (int i = 0; i < 4; ++i)
        t[ty + i * 8][tx] = src[(size_t)(k0 + ty + i * 8) * 512 + n0 + tx];
    __syncthreads();
#pragma unroll
    for (int i = 0; i < 4; ++i)
        dst[(size_t)(n0 + ty + i * 8) * 1024 + k0 + tx] = f2bf(t[tx][ty + i * 8]);
}

// ---------- stage one 128x64 bf16 half-tile into an LDS region ----------
// LDS dest is LINEAR (wave-uniform base + lane*16, HW requirement). The read-side
// XOR swizzle (byte ^= (row&7)<<4) is applied INVERSELY to the global source
// address so swizzled reads see the right data (both-sides-or-neither, rule #21).
__device__ __forceinline__ void stage_half(const u16* g, int gstride, u16* region, int tid) {
#pragma unroll
    for (int rd = 0; rd < 2; ++rd) {
        int ob = rd * 8192 + ((tid >> 6) << 10);   // wave-uniform byte base
        int o = ob + ((tid & 63) << 4);            // this lane's dest byte
        int row = o >> 7;
        int cb = (o & 127) ^ ((row & 7) << 4);     // inverse-swizzled source column-bytes
        const u16* gp = g + (size_t)row * gstride + (cb >> 1);
        __builtin_amdgcn_global_load_lds((as1p)(void*)gp, (as3p)(void*)(region + (ob >> 1)), 16, 0, 0);
    }
}

// ---------- swizzled LDS fragment read (ds_read_b128) ----------
__device__ __forceinline__ bf16x8 ld_frag(const u16* region, int r, int kb) {
    int byte = (r << 7) + (kb ^ ((r & 7) << 4));
    return *(const bf16x8*)((const char*)region + byte);
}

__device__ __forceinline__ void read_a(const u16* reg, int ra, int kbb, bf16x8 (&a)[4][2]) {
#pragma unroll
    for (int m4 = 0; m4 < 4; ++m4)
#pragma unroll
        for (int q = 0; q < 2; ++q)
            a[m4][q] = ld_frag(reg, ra + m4 * 16, q * 64 + kbb);
}

__device__ __forceinline__ void read_b(const u16* reg, int rb, int kbb, bf16x8 (&b)[2][2]) {
#pragma unroll
    for (int n2 = 0; n2 < 2; ++n2)
#pragma unroll
        for (int q = 0; q < 2; ++q)
            b[n2][q] = ld_frag(reg, rb + n2 * 16, q * 64 + kbb);
}

template<int MH, int NH>
__device__ __forceinline__ void mfma_q(f32x4 (&acc)[8][4], const bf16x8 (&a)[4][2],
                                       const bf16x8 (&b)[2][2]) {
    __builtin_amdgcn_s_setprio(1);
#pragma unroll
    for (int q = 0; q < 2; ++q)
#pragma unroll
        for (int m4 = 0; m4 < 4; ++m4)
#pragma unroll
            for (int n2 = 0; n2 < 2; ++n2)
                acc[MH * 4 + m4][NH * 2 + n2] = __builtin_amdgcn_mfma_f32_16x16x32_bf16(
                    a[m4][q], b[n2][q], acc[MH * 4 + m4][NH * 2 + n2], 0, 0, 0);
    __builtin_amdgcn_s_setprio(0);
}

// ---------- 256x256 8-phase K-loop core. K=1024 (16 tiles of BK=64). ----------
// A = [AX (k<512) | AH (k>=512)], row stride 512. B = W^T rows (output cols), stride 1024.
// Regions: [buf][0]=A0,[1]=A1,[2]=B0,[3]=B1, each 128x64 bf16 = 16 KiB. Total 128 KiB.
__device__ __forceinline__ void gemm_core(const u16* AX, const u16* AH, const u16* BW,
                                          u16* lds, int tid, f32x4 (&acc)[8][4]) {
    const int l = tid & 63, w = tid >> 6;
    const int wr = w >> 2, wc = w & 3;
    const int fr = l & 15;
    const int kbb = (l >> 4) << 4;
    const int ra = wr * 64 + fr;
    const int rb = wc * 32 + fr;

#define RG(b, g) (lds + ((b) * 4 + (g)) * 8192)
    auto ap = [&](int t, int h) -> const u16* {
        const u16* base = (t < 8) ? (AX + t * 64) : (AH + (t - 8) * 64);
        return base + (size_t)h * (128 * 512);
    };
    auto bp = [&](int t, int h) -> const u16* {
        return BW + (size_t)h * (128 * 1024) + t * 64;
    };

    // prologue: tile0 (4 halves) + A0,B0 of tile1. vmcnt(4) retires tile0.
    stage_half(ap(0, 0), 512,  RG(0, 0), tid);
    stage_half(bp(0, 0), 1024, RG(0, 2), tid);
    stage_half(bp(0, 1), 1024, RG(0, 3), tid);
    stage_half(ap(0, 1), 512,  RG(0, 1), tid);
    stage_half(ap(1, 0), 512,  RG(1, 0), tid);
    stage_half(bp(1, 0), 1024, RG(1, 2), tid);
    VMW4(); BAR();

    bf16x8 a[4][2], b0[2][2], b1[2][2];

    for (int i = 0; i < 7; ++i) {
        int t = 2 * i;
        // ---- tile t (buf0) ----
        read_a(RG(0, 0), ra, kbb, a); read_b(RG(0, 2), rb, kbb, b0);
        stage_half(bp(t + 1, 1), 1024, RG(1, 3), tid);              // P1: B1(t+1)
        BAR(); LGKM0(); mfma_q<0, 0>(acc, a, b0); BAR();
        read_b(RG(0, 3), rb, kbb, b1);
        stage_half(ap(t + 1, 1), 512, RG(1, 1), tid);               // P2: A1(t+1)
        BAR(); LGKM0(); mfma_q<0, 1>(acc, a, b1); BAR();
        read_a(RG(0, 1), ra, kbb, a);
        stage_half(ap(t + 2, 0), 512, RG(0, 0), tid);               // P3: A0(t+2)
        BAR(); LGKM0(); mfma_q<1, 1>(acc, a, b1); BAR();
        stage_half(bp(t + 2, 0), 1024, RG(0, 2), tid);              // P4: B0(t+2)
        BAR(); LGKM0(); mfma_q<1, 0>(acc, a, b0); VMW4(); BAR();
        // ---- tile t+1 (buf1) ----
        read_a(RG(1, 0), ra, kbb, a); read_b(RG(1, 2), rb, kbb, b0);
        stage_half(bp(t + 2, 1), 1024, RG(0, 3), tid);              // P5: B1(t+2)
        BAR(); LGKM0(); mfma_q<0, 0>(acc, a, b0); BAR();
        read_b(RG(1, 3), rb, kbb, b1);
        stage_half(ap(t + 2, 1), 512, RG(0, 1), tid);               // P6: A1(t+2)
        BAR(); LGKM0(); mfma_q<0, 1>(acc, a, b1); BAR();
        read_a(RG(1, 1), ra, kbb, a);
        stage_half(ap(t + 3, 0), 512, RG(1, 0), tid);               // P7: A0(t+3)
        BAR(); LGKM0(); mfma_q<1, 1>(acc, a, b1); BAR();
        stage_half(bp(t + 3, 0), 1024, RG(1, 2), tid);              // P8: B0(t+3)
        BAR(); LGKM0(); mfma_q<1, 0>(acc, a, b0); VMW4(); BAR();
    }
    // ---- tail: tile 14 (buf0) ----
    read_a(RG(0, 0), ra, kbb, a); read_b(RG(0, 2), rb, kbb, b0);
    stage_half(bp(15, 1), 1024, RG(1, 3), tid);
    BAR(); LGKM0(); mfma_q<0, 0>(acc, a, b0); BAR();
    read_b(RG(0, 3), rb, kbb, b1);
    stage_half(ap(15, 1), 512, RG(1, 1), tid);
    BAR(); LGKM0(); mfma_q<0, 1>(acc, a, b1); BAR();
    read_a(RG(0, 1), ra, kbb, a);
    BAR(); LGKM0(); mfma_q<1, 1>(acc, a, b1); BAR();
    BAR(); LGKM0(); mfma_q<1, 0>(acc, a, b0); VMW0(); BAR();
    // ---- tail: tile 15 (buf1), no stages ----
    read_a(RG(1, 0), ra, kbb, a); read_b(RG(1, 2), rb, kbb, b0);
    BAR(); LGKM0(); mfma_q<0, 0>(acc, a, b0); BAR();
    read_b(RG(1, 3), rb, kbb, b1);
    BAR(); LGKM0(); mfma_q<0, 1>(acc, a, b1); BAR();
    read_a(RG(1, 1), ra, kbb, a);
    BAR(); LGKM0(); mfma_q<1, 1>(acc, a, b1); BAR();
    BAR(); LGKM0(); mfma_q<1, 0>(acc, a, b0);
#undef RG
}

// ---------- GEMM1: [X|H] @ [Wz|Wr]^T -> zg (f32), rgh (bf16) ----------
__global__ __launch_bounds__(512, 2) void gemm1_k(
    const u16* __restrict__ Xb, const u16* __restrict__ Hb, const u16* __restrict__ Wt,
    const float* __restrict__ hp, const float* __restrict__ ub, const float* __restrict__ rb_,
    float* __restrict__ zg, u16* __restrict__ rgh) {
    extern __shared__ u16 lds[];
    int tid = threadIdx.x;
    int bid = blockIdx.x;
    int swz = (bid & 7) * 32 + (bid >> 3);          // 256 wgs, bijective XCD swizzle
    int mb = swz >> 2, nb = swz & 3;
    size_t m0 = (size_t)mb * 256; int n0 = nb * 256;

    f32x4 acc[8][4];
#pragma unroll
    for (int m = 0; m < 8; ++m)
#pragma unroll
        for (int n = 0; n < 4; ++n) acc[m][n] = (f32x4){0.f, 0.f, 0.f, 0.f};

    gemm_core(Xb + m0 * 512, Hb + m0 * 512, Wt + (size_t)n0 * 1024, lds, tid, acc);

    const int l = tid & 63, w = tid >> 6, wr = w >> 2, wc = w & 3;
    bool isZ = (n0 < 512);
#pragma unroll
    for (int n = 0; n < 4; ++n) {
        int col = n0 + (n < 2 ? 0 : 128) + wc * 32 + (n & 1) * 16 + (l & 15);
        int c = isZ ? col : col - 512;
        float bias = isZ ? ub[c] : rb_[c];
#pragma unroll
        for (int m = 0; m < 8; ++m) {
            int rowb = (int)m0 + (m < 4 ? 0 : 128) + wr * 64 + (m & 3) * 16 + ((l >> 4) << 2);
#pragma unroll
            for (int r = 0; r < 4; ++r) {
                int row = rowb + r;
                float v = acc[m][n][r] + bias;
                float s = 1.f / (1.f + __expf(-v));
                if (isZ) zg[(size_t)row * 512 + c] = s;
                else     rgh[(size_t)row * 512 + c] = f2bf(s * hp[(size_t)row * 512 + c]);
            }
        }
    }
}

// ---------- GEMM2: [X|rgh] @ Wh -> ht (f32) ----------
__global__ __launch_bounds__(512, 2) void gemm2_k(
    const u16* __restrict__ Xb, const u16* __restrict__ rgh, const u16* __restrict__ Wt,
    const float* __restrict__ hp, const float* __restrict__ zg, const float* __restrict__ hb,
    float* __restrict__ out) {
    extern __shared__ u16 lds[];
    int tid = threadIdx.x;
    int bid = blockIdx.x;
    int swz = (bid & 7) * 16 + (bid >> 3);          // 128 wgs, bijective
    int mb = swz >> 1, nb = swz & 1;
    size_t m0 = (size_t)mb * 256; int n0 = nb * 256;

    f32x4 acc[8][4];
#pragma unroll
    for (int m = 0; m < 8; ++m)
#pragma unroll
        for (int n = 0; n < 4; ++n) acc[m][n] = (f32x4){0.f, 0.f, 0.f, 0.f};

    gemm_core(Xb + m0 * 512, rgh + m0 * 512, Wt + (size_t)n0 * 1024, lds, tid, acc);

    const int l = tid & 63, w = tid >> 6, wr = w >> 2, wc = w & 3;
#pragma unroll
    for (int n = 0; n < 4; ++n) {
        int col = n0 + (n < 2 ? 0 : 128) + wc * 32 + (n & 1) * 16 + (l & 15);
        float bias = hb[col];
#pragma unroll
        for (int m = 0; m < 8; ++m) {
            int rowb = (int)m0 + (m < 4 ? 0 : 128) + wr * 64 + (m & 3) * 16 + ((l >> 4) << 2);
#pragma unroll
            for (int r = 0; r < 4; ++r) {
                int row = rowb + r;
                float v = acc[m][n][r] + bias;
                float t = tanhf(v);
                float h0 = hp[(size_t)row * 512 + col];
                float z = zg[(size_t)row * 512 + col];
                out[(size_t)row * 512 + col] = h0 + z * (t - h0);
            }
        }
    }
}

extern "C" void kernel_launch(void* const* d_in, const int* in_sizes, int n_in,
                              void* d_out, int out_size, void* d_ws, size_t ws_size,
                              hipStream_t stream) {
    const float* x  = (const float*)d_in[0];
    const float* h  = (const float*)d_in[1];
    const float* wz = (const float*)d_in[2];
    const float* wr = (const float*)d_in[3];
    const float* wh = (const float*)d_in[4];
    const float* ub = (const float*)d_in[5];
    const float* rb = (const float*)d_in[6];
    const float* hb = (const float*)d_in[7];
    float* out = (float*)d_out;

    const int B = 16384;
    char* ws = (char*)d_ws;
    size_t off = 0;
    u16* Xb  = (u16*)(ws + off); off += (size_t)B * 512 * 2;
    u16* Hb  = (u16*)(ws + off); off += (size_t)B * 512 * 2;
    u16* Wzr = (u16*)(ws + off); off += (size_t)1024 * 1024 * 2;
    u16* Wht = (u16*)(ws + off); off += (size_t)512 * 1024 * 2;
    u16* rgh = (u16*)(ws + off); off += (size_t)B * 512 * 2;
    float* zg = (float*)(ws + off); off += (size_t)B * 512 * 4;

    hipFuncSetAttribute((const void*)gemm1_k, hipFuncAttributeMaxDynamicSharedMemorySize, 131072);
    hipFuncSetAttribute((const void*)gemm2_k, hipFuncAttributeMaxDynamicSharedMemorySize, 131072);

    cvt_xh<<<2048, 256, 0, stream>>>(x, h, Xb, Hb, B * 512 / 4);

    dim3 tb(32, 8), tg(16, 32);
    tr_cvt<<<tg, tb, 0, stream>>>(wz, Wzr);
    tr_cvt<<<tg, tb, 0, stream>>>(wr, Wzr + (size_t)512 * 1024);
    tr_cvt<<<tg, tb, 0, stream>>>(wh, Wht);

    gemm1_k<<<256, 512, 131072, stream>>>(Xb, Hb, Wzr, h, ub, rb, zg, rgh);
    gemm2_k<<<128, 512, 131072, stream>>>(Xb, rgh, Wht, h, zg, hb, out);
}

// Round 3
// 156.396 us; speedup vs baseline: 1.4262x; 1.4262x over previous
//
#include <hip/hip_runtime.h>
#include <hip/hip_bf16.h>
#include <math.h>

typedef __attribute__((ext_vector_type(4))) float f32x4;
typedef __bf16 bf16x8 __attribute__((ext_vector_type(8)));
typedef unsigned short u16;
typedef void __attribute__((address_space(1))) * as1p;
typedef void __attribute__((address_space(3))) * as3p;

#define BAR() __builtin_amdgcn_s_barrier()
#define LGKM0() asm volatile("s_waitcnt lgkmcnt(0)" ::: "memory")
#define VMW4() asm volatile("s_waitcnt vmcnt(4)" ::: "memory")
#define VMW0() asm volatile("s_waitcnt vmcnt(0)" ::: "memory")

__device__ __forceinline__ unsigned short f2bf(float f) {
    union { float f; unsigned int u; } v; v.f = f;
    unsigned int u = v.u;
    u += 0x7fffu + ((u >> 16) & 1u);   // RNE
    return (unsigned short)(u >> 16);
}

__device__ __forceinline__ float fast_tanh(float v) {
    float vc = fminf(fmaxf(v, -15.f), 15.f);
    float e = __expf(2.f * vc);
    return (e - 1.f) / (e + 1.f);
}

// ---------- prepass: fp32 -> bf16 for X, h_prev ----------
__global__ void cvt_xh(const float* __restrict__ x, const float* __restrict__ h,
                       u16* __restrict__ xb, u16* __restrict__ hb, int n4) {
    int i = blockIdx.x * blockDim.x + threadIdx.x;
    int stride = gridDim.x * blockDim.x;
    const float4* x4 = (const float4*)x;
    const float4* h4 = (const float4*)h;
    ushort4* xb4 = (ushort4*)xb;
    ushort4* hb4 = (ushort4*)hb;
    for (; i < n4; i += stride) {
        float4 v = x4[i];
        xb4[i] = make_ushort4(f2bf(v.x), f2bf(v.y), f2bf(v.z), f2bf(v.w));
        float4 w = h4[i];
        hb4[i] = make_ushort4(f2bf(w.x), f2bf(w.y), f2bf(w.z), f2bf(w.w));
    }
}

// ---------- prepass: transpose+convert weight fp32 [1024][512] -> bf16 [512][1024] ----------
__global__ void tr_cvt(const float* __restrict__ src, u16* __restrict__ dst) {
    __shared__ float t[32][33];
    int n0 = blockIdx.x * 32;
    int k0 = blockIdx.y * 32;
    int tx = threadIdx.x, ty = threadIdx.y;
#pragma unroll
    for (int i = 0; i < 4; ++i)
        t[ty + i * 8][tx] = src[(size_t)(k0 + ty + i * 8) * 512 + n0 + tx];
    __syncthreads();
#pragma unroll
    for (int i = 0; i < 4; ++i)
        dst[(size_t)(n0 + ty + i * 8) * 1024 + k0 + tx] = f2bf(t[tx][ty + i * 8]);
}

// ================= gemm1: 256x256 8-phase (T2+T3+T4+T5) =================

// stage one 128x64 bf16 half-tile; linear LDS dest, inverse-swizzled global src (rule #21)
__device__ __forceinline__ void stage_half(const u16* g, int gstride, u16* region, int tid) {
#pragma unroll
    for (int rd = 0; rd < 2; ++rd) {
        int ob = rd * 8192 + ((tid >> 6) << 10);
        int o = ob + ((tid & 63) << 4);
        int row = o >> 7;
        int cb = (o & 127) ^ ((row & 7) << 4);
        const u16* gp = g + (size_t)row * gstride + (cb >> 1);
        __builtin_amdgcn_global_load_lds((as1p)(void*)gp, (as3p)(void*)(region + (ob >> 1)), 16, 0, 0);
    }
}

__device__ __forceinline__ bf16x8 ld_frag(const u16* region, int r, int kb) {
    int byte = (r << 7) + (kb ^ ((r & 7) << 4));
    return *(const bf16x8*)((const char*)region + byte);
}

__device__ __forceinline__ void read_a(const u16* reg, int ra, int kbb, bf16x8 (&a)[4][2]) {
#pragma unroll
    for (int m4 = 0; m4 < 4; ++m4)
#pragma unroll
        for (int q = 0; q < 2; ++q)
            a[m4][q] = ld_frag(reg, ra + m4 * 16, q * 64 + kbb);
}

__device__ __forceinline__ void read_b(const u16* reg, int rb, int kbb, bf16x8 (&b)[2][2]) {
#pragma unroll
    for (int n2 = 0; n2 < 2; ++n2)
#pragma unroll
        for (int q = 0; q < 2; ++q)
            b[n2][q] = ld_frag(reg, rb + n2 * 16, q * 64 + kbb);
}

template<int MH, int NH>
__device__ __forceinline__ void mfma_q(f32x4 (&acc)[8][4], const bf16x8 (&a)[4][2],
                                       const bf16x8 (&b)[2][2]) {
    __builtin_amdgcn_s_setprio(1);
#pragma unroll
    for (int q = 0; q < 2; ++q)
#pragma unroll
        for (int m4 = 0; m4 < 4; ++m4)
#pragma unroll
            for (int n2 = 0; n2 < 2; ++n2)
                acc[MH * 4 + m4][NH * 2 + n2] = __builtin_amdgcn_mfma_f32_16x16x32_bf16(
                    a[m4][q], b[n2][q], acc[MH * 4 + m4][NH * 2 + n2], 0, 0, 0);
    __builtin_amdgcn_s_setprio(0);
}

__device__ __forceinline__ void gemm_core(const u16* AX, const u16* AH, const u16* BW,
                                          u16* lds, int tid, f32x4 (&acc)[8][4]) {
    const int l = tid & 63, w = tid >> 6;
    const int wr = w >> 2, wc = w & 3;
    const int fr = l & 15;
    const int kbb = (l >> 4) << 4;
    const int ra = wr * 64 + fr;
    const int rb = wc * 32 + fr;

#define RG(b, g) (lds + ((b) * 4 + (g)) * 8192)
    auto ap = [&](int t, int h) -> const u16* {
        const u16* base = (t < 8) ? (AX + t * 64) : (AH + (t - 8) * 64);
        return base + (size_t)h * (128 * 512);
    };
    auto bp = [&](int t, int h) -> const u16* {
        return BW + (size_t)h * (128 * 1024) + t * 64;
    };

    stage_half(ap(0, 0), 512,  RG(0, 0), tid);
    stage_half(bp(0, 0), 1024, RG(0, 2), tid);
    stage_half(bp(0, 1), 1024, RG(0, 3), tid);
    stage_half(ap(0, 1), 512,  RG(0, 1), tid);
    stage_half(ap(1, 0), 512,  RG(1, 0), tid);
    stage_half(bp(1, 0), 1024, RG(1, 2), tid);
    VMW4(); BAR();

    bf16x8 a[4][2], b0[2][2], b1[2][2];

    for (int i = 0; i < 7; ++i) {
        int t = 2 * i;
        read_a(RG(0, 0), ra, kbb, a); read_b(RG(0, 2), rb, kbb, b0);
        stage_half(bp(t + 1, 1), 1024, RG(1, 3), tid);
        BAR(); LGKM0(); mfma_q<0, 0>(acc, a, b0); BAR();
        read_b(RG(0, 3), rb, kbb, b1);
        stage_half(ap(t + 1, 1), 512, RG(1, 1), tid);
        BAR(); LGKM0(); mfma_q<0, 1>(acc, a, b1); BAR();
        read_a(RG(0, 1), ra, kbb, a);
        stage_half(ap(t + 2, 0), 512, RG(0, 0), tid);
        BAR(); LGKM0(); mfma_q<1, 1>(acc, a, b1); BAR();
        stage_half(bp(t + 2, 0), 1024, RG(0, 2), tid);
        BAR(); LGKM0(); mfma_q<1, 0>(acc, a, b0); VMW4(); BAR();
        read_a(RG(1, 0), ra, kbb, a); read_b(RG(1, 2), rb, kbb, b0);
        stage_half(bp(t + 2, 1), 1024, RG(0, 3), tid);
        BAR(); LGKM0(); mfma_q<0, 0>(acc, a, b0); BAR();
        read_b(RG(1, 3), rb, kbb, b1);
        stage_half(ap(t + 2, 1), 512, RG(0, 1), tid);
        BAR(); LGKM0(); mfma_q<0, 1>(acc, a, b1); BAR();
        read_a(RG(1, 1), ra, kbb, a);
        stage_half(ap(t + 3, 0), 512, RG(1, 0), tid);
        BAR(); LGKM0(); mfma_q<1, 1>(acc, a, b1); BAR();
        stage_half(bp(t + 3, 0), 1024, RG(1, 2), tid);
        BAR(); LGKM0(); mfma_q<1, 0>(acc, a, b0); VMW4(); BAR();
    }
    read_a(RG(0, 0), ra, kbb, a); read_b(RG(0, 2), rb, kbb, b0);
    stage_half(bp(15, 1), 1024, RG(1, 3), tid);
    BAR(); LGKM0(); mfma_q<0, 0>(acc, a, b0); BAR();
    read_b(RG(0, 3), rb, kbb, b1);
    stage_half(ap(15, 1), 512, RG(1, 1), tid);
    BAR(); LGKM0(); mfma_q<0, 1>(acc, a, b1); BAR();
    read_a(RG(0, 1), ra, kbb, a);
    BAR(); LGKM0(); mfma_q<1, 1>(acc, a, b1); BAR();
    BAR(); LGKM0(); mfma_q<1, 0>(acc, a, b0); VMW0(); BAR();
    read_a(RG(1, 0), ra, kbb, a); read_b(RG(1, 2), rb, kbb, b0);
    BAR(); LGKM0(); mfma_q<0, 0>(acc, a, b0); BAR();
    read_b(RG(1, 3), rb, kbb, b1);
    BAR(); LGKM0(); mfma_q<0, 1>(acc, a, b1); BAR();
    read_a(RG(1, 1), ra, kbb, a);
    BAR(); LGKM0(); mfma_q<1, 1>(acc, a, b1); BAR();
    BAR(); LGKM0(); mfma_q<1, 0>(acc, a, b0);
#undef RG
}

__global__ __launch_bounds__(512, 2) void gemm1_k(
    const u16* __restrict__ Xb, const u16* __restrict__ Hb, const u16* __restrict__ Wt,
    const float* __restrict__ hp, const float* __restrict__ ub, const float* __restrict__ rb_,
    float* __restrict__ zg, u16* __restrict__ rgh) {
    extern __shared__ u16 lds[];
    int tid = threadIdx.x;
    int bid = blockIdx.x;
    int swz = (bid & 7) * 32 + (bid >> 3);
    int mb = swz >> 2, nb = swz & 3;
    size_t m0 = (size_t)mb * 256; int n0 = nb * 256;

    f32x4 acc[8][4];
#pragma unroll
    for (int m = 0; m < 8; ++m)
#pragma unroll
        for (int n = 0; n < 4; ++n) acc[m][n] = (f32x4){0.f, 0.f, 0.f, 0.f};

    gemm_core(Xb + m0 * 512, Hb + m0 * 512, Wt + (size_t)n0 * 1024, lds, tid, acc);

    const int l = tid & 63, w = tid >> 6, wr = w >> 2, wc = w & 3;
    bool isZ = (n0 < 512);
#pragma unroll
    for (int n = 0; n < 4; ++n) {
        int col = n0 + (n < 2 ? 0 : 128) + wc * 32 + (n & 1) * 16 + (l & 15);
        int c = isZ ? col : col - 512;
        float bias = isZ ? ub[c] : rb_[c];
#pragma unroll
        for (int m = 0; m < 8; ++m) {
            int rowb = (int)m0 + (m < 4 ? 0 : 128) + wr * 64 + (m & 3) * 16 + ((l >> 4) << 2);
#pragma unroll
            for (int r = 0; r < 4; ++r) {
                int row = rowb + r;
                float v = acc[m][n][r] + bias;
                float s = 1.f / (1.f + __expf(-v));
                if (isZ) zg[(size_t)row * 512 + c] = s;
                else     rgh[(size_t)row * 512 + c] = f2bf(s * hp[(size_t)row * 512 + c]);
            }
        }
    }
}

// ================= gemm2: round-1 m97-style 128x128, 2 blocks/CU =================

__device__ __forceinline__ void stage128x64_lin(const u16* g, int gstride,
                                                u16* lds, int tid) {
    int w = tid >> 6;
    int l = tid & 63;
#pragma unroll
    for (int i = 0; i < 4; ++i) {
        int o = i * 4096 + w * 1024 + l * 16;
        int row = o >> 7;
        int ke = (o & 127) >> 1;
        const u16* gp = g + (size_t)row * gstride + ke;
        u16* lp = lds + ((i * 4096 + w * 1024) >> 1);
        __builtin_amdgcn_global_load_lds((as1p)(void*)gp, (as3p)(void*)lp, 16, 0, 0);
    }
}

__global__ __launch_bounds__(256) void gemm2_k(
    const u16* __restrict__ Xb, const u16* __restrict__ rgh, const u16* __restrict__ Wt,
    const float* __restrict__ hp, const float* __restrict__ zg, const float* __restrict__ hb,
    float* __restrict__ out) {
    __shared__ u16 ldsA[128 * 64];
    __shared__ u16 ldsB[128 * 64];
    int tid = threadIdx.x;
    int l = tid & 63, w = tid >> 6;
    int wr = w >> 1, wc = w & 1;
    int bidl = blockIdx.y * 4 + blockIdx.x;          // 0..511
    int swz = (bidl & 7) * 64 + (bidl >> 3);         // bijective XCD swizzle
    int mb = swz >> 2, nb = swz & 3;
    int m0 = mb * 128;
    int n0 = nb * 128;
    f32x4 acc[4][4];
#pragma unroll
    for (int m = 0; m < 4; ++m)
#pragma unroll
        for (int n = 0; n < 4; ++n) acc[m][n] = (f32x4){0.f, 0.f, 0.f, 0.f};

    int fr = l & 15;
    int fk = (l >> 4) << 3;

    for (int k0 = 0; k0 < 1024; k0 += 64) {
        const u16* gA = (k0 < 512) ? (Xb + (size_t)m0 * 512 + k0)
                                   : (rgh + (size_t)m0 * 512 + (k0 - 512));
        stage128x64_lin(gA, 512, ldsA, tid);
        stage128x64_lin(Wt + (size_t)n0 * 1024 + k0, 1024, ldsB, tid);
        __syncthreads();
#pragma unroll
        for (int kk = 0; kk < 64; kk += 32) {
            bf16x8 a[4], b[4];
#pragma unroll
            for (int m = 0; m < 4; ++m)
                a[m] = *(const bf16x8*)&ldsA[(wr * 64 + m * 16 + fr) * 64 + kk + fk];
#pragma unroll
            for (int n = 0; n < 4; ++n)
                b[n] = *(const bf16x8*)&ldsB[(wc * 64 + n * 16 + fr) * 64 + kk + fk];
#pragma unroll
            for (int m = 0; m < 4; ++m)
#pragma unroll
                for (int n = 0; n < 4; ++n)
                    acc[m][n] = __builtin_amdgcn_mfma_f32_16x16x32_bf16(a[m], b[n], acc[m][n], 0, 0, 0);
        }
        __syncthreads();
    }

    int colb = n0 + wc * 64;
    int rowb = m0 + wr * 64 + ((l >> 4) << 2);
#pragma unroll
    for (int n = 0; n < 4; ++n) {
        int col = colb + n * 16 + (l & 15);
        float bias = hb[col];
#pragma unroll
        for (int m = 0; m < 4; ++m) {
            int row0 = rowb + m * 16;
#pragma unroll
            for (int r = 0; r < 4; ++r) {
                int row = row0 + r;
                float v = acc[m][n][r] + bias;
                float t = fast_tanh(v);
                float h0 = hp[(size_t)row * 512 + col];
                float z = zg[(size_t)row * 512 + col];
                out[(size_t)row * 512 + col] = h0 + z * (t - h0);
            }
        }
    }
}

extern "C" void kernel_launch(void* const* d_in, const int* in_sizes, int n_in,
                              void* d_out, int out_size, void* d_ws, size_t ws_size,
                              hipStream_t stream) {
    const float* x  = (const float*)d_in[0];
    const float* h  = (const float*)d_in[1];
    const float* wz = (const float*)d_in[2];
    const float* wr = (const float*)d_in[3];
    const float* wh = (const float*)d_in[4];
    const float* ub = (const float*)d_in[5];
    const float* rb = (const float*)d_in[6];
    const float* hb = (const float*)d_in[7];
    float* out = (float*)d_out;

    const int B = 16384;
    char* ws = (char*)d_ws;
    size_t off = 0;
    u16* Xb  = (u16*)(ws + off); off += (size_t)B * 512 * 2;
    u16* Hb  = (u16*)(ws + off); off += (size_t)B * 512 * 2;
    u16* Wzr = (u16*)(ws + off); off += (size_t)1024 * 1024 * 2;
    u16* Wht = (u16*)(ws + off); off += (size_t)512 * 1024 * 2;
    u16* rgh = (u16*)(ws + off); off += (size_t)B * 512 * 2;
    float* zg = (float*)(ws + off); off += (size_t)B * 512 * 4;

    hipFuncSetAttribute((const void*)gemm1_k, hipFuncAttributeMaxDynamicSharedMemorySize, 131072);

    cvt_xh<<<2048, 256, 0, stream>>>(x, h, Xb, Hb, B * 512 / 4);

    dim3 tb(32, 8), tg(16, 32);
    tr_cvt<<<tg, tb, 0, stream>>>(wz, Wzr);
    tr_cvt<<<tg, tb, 0, stream>>>(wr, Wzr + (size_t)512 * 1024);
    tr_cvt<<<tg, tb, 0, stream>>>(wh, Wht);

    gemm1_k<<<256, 512, 131072, stream>>>(Xb, Hb, Wzr, h, ub, rb, zg, rgh);
    gemm2_k<<<dim3(4, 128), 256, 0, stream>>>(Xb, rgh, Wht, h, zg, hb, out);
}